// Round 1
// baseline (1120.752 us; speedup 1.0000x reference)
//
#include <hip/hip_runtime.h>
#include <float.h>
#include <math.h>

#pragma clang fp contract(off)

#define R 8192
#define NCLS 80
#define SC 81          // scores row width (K+1)
#define TOPK_N 100
#define SCORE_THRESH 0.05f
#define NMS_THRESH 0.5f
#define NEGV -1000000000.0f

// workspace layout (bytes)
#define BOXC_OFF   0            // float4[R]        131072
#define AREA_OFF   131072       // float[R]          32768
#define VALID_OFF  163840       // int[R]            32768
#define CNT_OFF    196608       // uint (padded)        16
#define ENT_OFF    196624       // u64 entries[cap]

__device__ __forceinline__ bool finitef(float x) {
    return fabsf(x) <= FLT_MAX;   // false for NaN and +-inf
}

// ---------------- kernel A: clip boxes, validity, areas, zero counter ---------------
__global__ void prep_kernel(const float* __restrict__ boxes,
                            const float* __restrict__ scores,
                            const int* __restrict__ imh,
                            const int* __restrict__ imw,
                            float4* __restrict__ boxes_c,
                            float* __restrict__ area,
                            int* __restrict__ valid,
                            unsigned int* __restrict__ counter) {
    int r = blockIdx.x * blockDim.x + threadIdx.x;
    if (r == 0) *counter = 0u;
    if (r >= R) return;
    float w = (float)(*imw), h = (float)(*imh);
    float x1 = boxes[r * 4 + 0];
    float y1 = boxes[r * 4 + 1];
    float x2 = boxes[r * 4 + 2];
    float y2 = boxes[r * 4 + 3];
    bool v = finitef(x1) && finitef(y1) && finitef(x2) && finitef(y2);
    for (int k = 0; k < SC; ++k) v = v && finitef(scores[r * SC + k]);
    float cx1 = fminf(fmaxf(x1, 0.f), w);
    float cy1 = fminf(fmaxf(y1, 0.f), h);
    float cx2 = fminf(fmaxf(x2, 0.f), w);
    float cy2 = fminf(fmaxf(y2, 0.f), h);
    boxes_c[r] = make_float4(cx1, cy1, cx2, cy2);
    area[r] = fmaxf(cx2 - cx1, 0.f) * fmaxf(cy2 - cy1, 0.f);
    valid[r] = v ? 1 : 0;
}

// ---------------- kernel B: per-class NMS (one block per class) ----------------
#define NMS_THREADS 256

__global__ __launch_bounds__(NMS_THREADS) void nms_kernel(
    const float* __restrict__ scores,
    const float4* __restrict__ boxes_c,
    const float* __restrict__ area,
    const int* __restrict__ valid,
    unsigned long long* __restrict__ entries,
    unsigned int* __restrict__ counter,
    int cap) {
    __shared__ float s_sc[R];                 // 32 KB
    __shared__ unsigned short s_id[R];        // 16 KB
    __shared__ unsigned int s_supp[R / 32];   // 1 KB
    __shared__ unsigned int s_keep[R / 32];   // 1 KB
    __shared__ int s_cnt;

    const int tid = threadIdx.x;
    const int k = blockIdx.x;

    if (tid == 0) s_cnt = 0;
    for (int i = tid; i < R / 32; i += NMS_THREADS) { s_supp[i] = 0u; s_keep[i] = 0u; }
    __syncthreads();

    // compact candidates: score > thresh && valid
    for (int r = tid; r < R; r += NMS_THREADS) {
        float sc = scores[r * SC + k];
        if (sc > SCORE_THRESH && valid[r]) {
            int p = atomicAdd(&s_cnt, 1);
            s_sc[p] = sc;
            s_id[p] = (unsigned short)r;
        }
    }
    __syncthreads();
    const int cnt = s_cnt;
    if (cnt == 0) return;

    int npad = 1;
    while (npad < cnt) npad <<= 1;
    for (int i = cnt + tid; i < npad; i += NMS_THREADS) {
        s_sc[i] = -INFINITY;
        s_id[i] = 0xFFFFu;
    }
    __syncthreads();

    // bitonic sort: descending score, ties -> ascending index (stable argsort(-s))
    for (int kk = 2; kk <= npad; kk <<= 1) {
        for (int j = kk >> 1; j > 0; j >>= 1) {
            for (int i = tid; i < npad; i += NMS_THREADS) {
                int ixj = i ^ j;
                if (ixj > i) {
                    float a = s_sc[i], b = s_sc[ixj];
                    unsigned short ia = s_id[i], ib = s_id[ixj];
                    bool b_before_a = (b > a) || (b == a && ib < ia);
                    bool ascending = ((i & kk) == 0);
                    if (b_before_a == ascending) {
                        s_sc[i] = b; s_sc[ixj] = a;
                        s_id[i] = ib; s_id[ixj] = ia;
                    }
                }
            }
            __syncthreads();
        }
    }

    // greedy NMS over sorted candidates
    for (int i = 0; i < cnt; ++i) {
        bool sup = (s_supp[i >> 5] >> (i & 31)) & 1u;   // uniform across block
        if (sup) continue;
        if (tid == 0) s_keep[i >> 5] |= (1u << (i & 31));
        const int bi = s_id[i];
        const float4 bb = boxes_c[bi];
        const float ai = area[bi];
        for (int j = i + 1 + tid; j < cnt; j += NMS_THREADS) {
            const int bj = s_id[j];
            const float4 bc = boxes_c[bj];
            float ltx = fmaxf(bb.x, bc.x), lty = fmaxf(bb.y, bc.y);
            float rbx = fminf(bb.z, bc.z), rby = fminf(bb.w, bc.w);
            float iw = fmaxf(rbx - ltx, 0.f), ih = fmaxf(rby - lty, 0.f);
            float inter = iw * ih;
            float uni = ai + area[bj] - inter + 1e-9f;
            float iou = inter / uni;
            if (iou > NMS_THRESH) atomicOr(&s_supp[j >> 5], 1u << (j & 31));
        }
        __syncthreads();
    }
    __syncthreads();

    // append kept entries: pack (flat_idx << 32) | score_bits
    for (int i = tid; i < cnt; i += NMS_THREADS) {
        if ((s_keep[i >> 5] >> (i & 31)) & 1u) {
            unsigned int pos = atomicAdd(counter, 1u);
            if ((int)pos < cap) {
                unsigned long long e =
                    ((unsigned long long)(unsigned int)(k * R + (int)s_id[i]) << 32) |
                    (unsigned long long)__float_as_uint(s_sc[i]);
                entries[pos] = e;
            }
        }
    }
}

// ---------------- kernel C: global top-100 + output formatting ----------------
#define TK_THREADS 1024

__global__ __launch_bounds__(TK_THREADS) void topk_kernel(
    const unsigned long long* __restrict__ entries,
    const unsigned int* __restrict__ counter,
    int cap,
    const float4* __restrict__ boxes_c,
    float* __restrict__ out) {
    __shared__ float w_s[TK_THREADS / 64];
    __shared__ int   w_f[TK_THREADS / 64];
    __shared__ float sel_s[TOPK_N];
    __shared__ int   sel_f[TOPK_N];
    __shared__ float cur_s;
    __shared__ int   cur_f;

    const int tid = threadIdx.x;
    int M = (int)*counter;
    if (M > cap) M = cap;

    if (tid == 0) { cur_s = INFINITY; cur_f = -1; }
    __syncthreads();

    for (int sel = 0; sel < TOPK_N; ++sel) {
        const float last_s = cur_s;
        const int   last_f = cur_f;
        float best_s = -INFINITY;
        int   best_f = 0x7FFFFFFF;
        for (int i = tid; i < M; i += TK_THREADS) {
            unsigned long long e = entries[i];
            float s = __uint_as_float((unsigned int)e);
            int   f = (int)(e >> 32);
            // strictly after the last selected key (score desc, flat asc)
            bool after = (s < last_s) || (s == last_s && f > last_f);
            if (after && (s > best_s || (s == best_s && f < best_f))) {
                best_s = s;
                best_f = f;
            }
        }
        // 64-lane wave reduction
        for (int off = 32; off > 0; off >>= 1) {
            float os = __shfl_down(best_s, off);
            int   of = __shfl_down(best_f, off);
            if (os > best_s || (os == best_s && of < best_f)) { best_s = os; best_f = of; }
        }
        const int wave = tid >> 6, lane = tid & 63;
        if (lane == 0) { w_s[wave] = best_s; w_f[wave] = best_f; }
        __syncthreads();
        if (tid == 0) {
            float bs = w_s[0]; int bf = w_f[0];
            for (int i = 1; i < TK_THREADS / 64; ++i) {
                if (w_s[i] > bs || (w_s[i] == bs && w_f[i] < bf)) { bs = w_s[i]; bf = w_f[i]; }
            }
            sel_s[sel] = bs; sel_f[sel] = bf;
            cur_s = bs; cur_f = bf;
        }
        __syncthreads();
    }

    if (tid < TOPK_N) {
        float s = sel_s[tid];
        int   f = sel_f[tid];
        bool dv = (s > NEGV * 0.5f);   // matches vals > NEG/2
        int r = f & (R - 1);
        int kc = f >> 13;
        float4 bb = dv ? boxes_c[r] : make_float4(0.f, 0.f, 0.f, 0.f);
        out[tid * 4 + 0] = bb.x;
        out[tid * 4 + 1] = bb.y;
        out[tid * 4 + 2] = bb.z;
        out[tid * 4 + 3] = bb.w;
        out[400 + tid] = dv ? s : 0.f;
        out[500 + tid] = dv ? (float)kc : -1.f;
        out[600 + tid] = dv ? (float)r : -1.f;
    }
}

extern "C" void kernel_launch(void* const* d_in, const int* in_sizes, int n_in,
                              void* d_out, int out_size, void* d_ws, size_t ws_size,
                              hipStream_t stream) {
    const float* boxes  = (const float*)d_in[0];
    const float* scores = (const float*)d_in[1];
    const int*   imh    = (const int*)d_in[2];
    const int*   imw    = (const int*)d_in[3];

    char* ws = (char*)d_ws;
    float4*             boxes_c = (float4*)(ws + BOXC_OFF);
    float*              area    = (float*)(ws + AREA_OFF);
    int*                valid   = (int*)(ws + VALID_OFF);
    unsigned int*       counter = (unsigned int*)(ws + CNT_OFF);
    unsigned long long* entries = (unsigned long long*)(ws + ENT_OFF);

    long long cap_ll = ((long long)ws_size - ENT_OFF) / 8;
    if (cap_ll < 0) cap_ll = 0;
    int cap = (cap_ll > (long long)(NCLS * R)) ? (NCLS * R) : (int)cap_ll;

    prep_kernel<<<R / 256, 256, 0, stream>>>(boxes, scores, imh, imw,
                                             boxes_c, area, valid, counter);
    nms_kernel<<<NCLS, NMS_THREADS, 0, stream>>>(scores, boxes_c, area, valid,
                                                 entries, counter, cap);
    topk_kernel<<<1, TK_THREADS, 0, stream>>>(entries, counter, cap, boxes_c,
                                              (float*)d_out);
}

// Round 2
// 457.838 us; speedup vs baseline: 2.4479x; 2.4479x over previous
//
#include <hip/hip_runtime.h>
#include <float.h>
#include <math.h>

#pragma clang fp contract(off)

#define R 8192
#define NCLS 80
#define SC 81          // scores row width (K+1)
#define TOPK_N 100
#define SCORE_THRESH 0.05f
#define NMS_THRESH 0.5f
#define NEGV -1000000000.0f

// workspace layout (bytes)
#define BOXC_OFF   0            // float4[R]        131072
#define AREA_OFF   131072       // float[R]          32768
#define VALID_OFF  163840       // int[R]            32768
#define CNT_OFF    196608       // uint (padded)        16
#define ENT_OFF    196624       // u64 entries[NCLS*100] = 64000 bytes
#define NENT       (NCLS * TOPK_N)   // 8000
#define NENT_PAD   8192

__device__ __forceinline__ bool finitef(float x) {
    return fabsf(x) <= FLT_MAX;   // false for NaN and +-inf
}

// ---------------- kernel A: clip boxes, validity, areas, zero counter+entries ------
__global__ void prep_kernel(const float* __restrict__ boxes,
                            const float* __restrict__ scores,
                            const int* __restrict__ imh,
                            const int* __restrict__ imw,
                            float4* __restrict__ boxes_c,
                            float* __restrict__ area,
                            int* __restrict__ valid,
                            unsigned int* __restrict__ counter,
                            unsigned long long* __restrict__ entries) {
    int r = blockIdx.x * blockDim.x + threadIdx.x;
    if (r == 0) *counter = 0u;
    if (r < NENT) entries[r] = 0ull;
    if (r >= R) return;
    float w = (float)(*imw), h = (float)(*imh);
    float x1 = boxes[r * 4 + 0];
    float y1 = boxes[r * 4 + 1];
    float x2 = boxes[r * 4 + 2];
    float y2 = boxes[r * 4 + 3];
    bool v = finitef(x1) && finitef(y1) && finitef(x2) && finitef(y2);
    for (int k = 0; k < SC; ++k) v = v && finitef(scores[r * SC + k]);
    float cx1 = fminf(fmaxf(x1, 0.f), w);
    float cy1 = fminf(fmaxf(y1, 0.f), h);
    float cx2 = fminf(fmaxf(x2, 0.f), w);
    float cy2 = fminf(fmaxf(y2, 0.f), h);
    boxes_c[r] = make_float4(cx1, cy1, cx2, cy2);
    area[r] = fmaxf(cx2 - cx1, 0.f) * fmaxf(cy2 - cy1, 0.f);
    valid[r] = v ? 1 : 0;
}

// ---------------- kernel B: per-class NMS (one block per class) ----------------
#define NMS_THREADS 256

__global__ __launch_bounds__(NMS_THREADS) void nms_kernel(
    const float* __restrict__ scores,
    const float4* __restrict__ boxes_c,
    const float* __restrict__ area,
    const int* __restrict__ valid,
    unsigned long long* __restrict__ entries,
    unsigned int* __restrict__ counter) {
    __shared__ float s_sc[R];                 // 32 KB
    __shared__ unsigned short s_id[R];        // 16 KB
    __shared__ unsigned int s_supp[R / 32];   // 1 KB
    __shared__ unsigned int s_keep[R / 32];   // 1 KB
    __shared__ unsigned int s_scan[NMS_THREADS];
    __shared__ int s_cnt;

    const int tid = threadIdx.x;
    const int k = blockIdx.x;

    if (tid == 0) s_cnt = 0;
    for (int i = tid; i < R / 32; i += NMS_THREADS) { s_supp[i] = 0u; s_keep[i] = 0u; }
    __syncthreads();

    // compact candidates: score > thresh && valid
    for (int r = tid; r < R; r += NMS_THREADS) {
        float sc = scores[r * SC + k];
        if (sc > SCORE_THRESH && valid[r]) {
            int p = atomicAdd(&s_cnt, 1);
            s_sc[p] = sc;
            s_id[p] = (unsigned short)r;
        }
    }
    __syncthreads();
    const int cnt = s_cnt;
    if (cnt == 0) return;

    int npad = 1;
    while (npad < cnt) npad <<= 1;
    for (int i = cnt + tid; i < npad; i += NMS_THREADS) {
        s_sc[i] = -INFINITY;
        s_id[i] = 0xFFFFu;
    }
    __syncthreads();

    // bitonic sort: descending score, ties -> ascending index (stable argsort(-s))
    for (int kk = 2; kk <= npad; kk <<= 1) {
        for (int j = kk >> 1; j > 0; j >>= 1) {
            for (int i = tid; i < npad; i += NMS_THREADS) {
                int ixj = i ^ j;
                if (ixj > i) {
                    float a = s_sc[i], b = s_sc[ixj];
                    unsigned short ia = s_id[i], ib = s_id[ixj];
                    bool b_before_a = (b > a) || (b == a && ib < ia);
                    bool ascending = ((i & kk) == 0);
                    if (b_before_a == ascending) {
                        s_sc[i] = b; s_sc[ixj] = a;
                        s_id[i] = ib; s_id[ixj] = ia;
                    }
                }
            }
            __syncthreads();
        }
    }

    // greedy NMS over sorted candidates
    for (int i = 0; i < cnt; ++i) {
        bool sup = (s_supp[i >> 5] >> (i & 31)) & 1u;   // uniform across block
        if (sup) continue;
        if (tid == 0) s_keep[i >> 5] |= (1u << (i & 31));
        const int bi = s_id[i];
        const float4 bb = boxes_c[bi];
        const float ai = area[bi];
        for (int j = i + 1 + tid; j < cnt; j += NMS_THREADS) {
            const int bj = s_id[j];
            const float4 bc = boxes_c[bj];
            float ltx = fmaxf(bb.x, bc.x), lty = fmaxf(bb.y, bc.y);
            float rbx = fminf(bb.z, bc.z), rby = fminf(bb.w, bc.w);
            float iw = fmaxf(rbx - ltx, 0.f), ih = fmaxf(rby - lty, 0.f);
            float inter = iw * ih;
            float uni = ai + area[bj] - inter + 1e-9f;
            float iou = inter / uni;
            if (iou > NMS_THRESH) atomicOr(&s_supp[j >> 5], 1u << (j & 31));
        }
        __syncthreads();
    }
    __syncthreads();

    // rank kept candidates (they are in sorted order) via popcount prefix scan,
    // emit only the per-class top-100 into fixed slots entries[k*100 + rank].
    unsigned int myword = s_keep[tid];
    unsigned int wsum = __popc(myword);
    s_scan[tid] = wsum;
    __syncthreads();
    for (int off = 1; off < NMS_THREADS; off <<= 1) {
        unsigned int v = (tid >= off) ? s_scan[tid - off] : 0u;
        __syncthreads();
        s_scan[tid] += v;
        __syncthreads();
    }
    const unsigned int total = s_scan[NMS_THREADS - 1];
    unsigned int rnk = s_scan[tid] - wsum;   // exclusive prefix for this word
    unsigned int bits = myword;
    while (bits) {
        int b = __ffs(bits) - 1;
        bits &= bits - 1;
        if (rnk < TOPK_N) {
            int i = (tid << 5) + b;
            unsigned long long e =
                ((unsigned long long)(unsigned int)(k * R + (int)s_id[i]) << 32) |
                (unsigned long long)__float_as_uint(s_sc[i]);
            entries[k * TOPK_N + rnk] = e;
        }
        rnk++;
    }
    if (tid == 0) {
        unsigned int add = total < TOPK_N ? total : TOPK_N;
        atomicAdd(counter, add);
    }
}

// ---------------- kernel C: bitonic sort of <=8000 entries in LDS + output ---------
#define TK_THREADS 1024

__global__ __launch_bounds__(TK_THREADS) void topk_kernel(
    const unsigned long long* __restrict__ entries,
    const unsigned int* __restrict__ counter,
    const float4* __restrict__ boxes_c,
    float* __restrict__ out) {
    __shared__ float s_sc[NENT_PAD];            // 32 KB
    __shared__ unsigned short s_pos[NENT_PAD];  // 16 KB

    const int tid = threadIdx.x;
    const int M = (int)*counter;   // total real entries (each has score > 0.05)

    for (int i = tid; i < NENT_PAD; i += TK_THREADS) {
        float sc = 0.f;
        if (i < NENT) sc = __uint_as_float((unsigned int)entries[i]);  // zero slots -> 0.0
        s_sc[i] = sc;
        s_pos[i] = (unsigned short)i;
    }
    __syncthreads();

    // bitonic sort: score desc, slot-pos asc (== reference (score desc, flat asc))
    for (int kk = 2; kk <= NENT_PAD; kk <<= 1) {
        for (int j = kk >> 1; j > 0; j >>= 1) {
            for (int i = tid; i < NENT_PAD; i += TK_THREADS) {
                int ixj = i ^ j;
                if (ixj > i) {
                    float a = s_sc[i], b = s_sc[ixj];
                    unsigned short pa = s_pos[i], pb = s_pos[ixj];
                    bool b_before_a = (b > a) || (b == a && pb < pa);
                    bool ascending = ((i & kk) == 0);
                    if (b_before_a == ascending) {
                        s_sc[i] = b; s_sc[ixj] = a;
                        s_pos[i] = pb; s_pos[ixj] = pa;
                    }
                }
            }
            __syncthreads();
        }
    }

    if (tid < TOPK_N) {
        bool dv = (tid < M);
        float s = s_sc[tid];
        int flat = 0;
        if (dv) flat = (int)(entries[s_pos[tid]] >> 32);
        int r = flat & (R - 1);
        int kc = flat >> 13;
        float4 bb = dv ? boxes_c[r] : make_float4(0.f, 0.f, 0.f, 0.f);
        out[tid * 4 + 0] = bb.x;
        out[tid * 4 + 1] = bb.y;
        out[tid * 4 + 2] = bb.z;
        out[tid * 4 + 3] = bb.w;
        out[400 + tid] = dv ? s : 0.f;
        out[500 + tid] = dv ? (float)kc : -1.f;
        out[600 + tid] = dv ? (float)r : -1.f;
    }
}

extern "C" void kernel_launch(void* const* d_in, const int* in_sizes, int n_in,
                              void* d_out, int out_size, void* d_ws, size_t ws_size,
                              hipStream_t stream) {
    const float* boxes  = (const float*)d_in[0];
    const float* scores = (const float*)d_in[1];
    const int*   imh    = (const int*)d_in[2];
    const int*   imw    = (const int*)d_in[3];

    char* ws = (char*)d_ws;
    float4*             boxes_c = (float4*)(ws + BOXC_OFF);
    float*              area    = (float*)(ws + AREA_OFF);
    int*                valid   = (int*)(ws + VALID_OFF);
    unsigned int*       counter = (unsigned int*)(ws + CNT_OFF);
    unsigned long long* entries = (unsigned long long*)(ws + ENT_OFF);

    prep_kernel<<<R / 256, 256, 0, stream>>>(boxes, scores, imh, imw,
                                             boxes_c, area, valid, counter, entries);
    nms_kernel<<<NCLS, NMS_THREADS, 0, stream>>>(scores, boxes_c, area, valid,
                                                 entries, counter);
    topk_kernel<<<1, TK_THREADS, 0, stream>>>(entries, counter, boxes_c,
                                              (float*)d_out);
}

// Round 3
// 150.148 us; speedup vs baseline: 7.4643x; 3.0492x over previous
//
#include <hip/hip_runtime.h>
#include <float.h>
#include <math.h>

#pragma clang fp contract(off)

#define R 8192
#define NCLS 80
#define SC 81          // scores row width (K+1)
#define TOPK_N 100
#define SCORE_THRESH 0.05f
#define NMS_THRESH 0.5f
#define NEGV -1000000000.0f

// workspace layout (bytes)
#define BOXC_OFF   0            // float4[R]        131072
#define AREA_OFF   131072       // float[R]          32768
#define VALID_OFF  163840       // int[R]            32768
#define CNT_OFF    196608       // uint (padded)        16
#define ENT_OFF    196624       // u64 entries[NCLS*100] = 64000 bytes
#define NENT       (NCLS * TOPK_N)   // 8000

__device__ __forceinline__ bool finitef(float x) {
    return fabsf(x) <= FLT_MAX;   // false for NaN and +-inf
}

// ---------------- kernel A: clip boxes, validity, areas, zero counter+entries ------
__global__ void prep_kernel(const float* __restrict__ boxes,
                            const float* __restrict__ scores,
                            const int* __restrict__ imh,
                            const int* __restrict__ imw,
                            float4* __restrict__ boxes_c,
                            float* __restrict__ area,
                            int* __restrict__ valid,
                            unsigned int* __restrict__ counter,
                            unsigned long long* __restrict__ entries) {
    int r = blockIdx.x * blockDim.x + threadIdx.x;
    if (r == 0) *counter = 0u;
    if (r < NENT) entries[r] = 0ull;
    if (r >= R) return;
    float w = (float)(*imw), h = (float)(*imh);
    float x1 = boxes[r * 4 + 0];
    float y1 = boxes[r * 4 + 1];
    float x2 = boxes[r * 4 + 2];
    float y2 = boxes[r * 4 + 3];
    bool v = finitef(x1) && finitef(y1) && finitef(x2) && finitef(y2);
#pragma unroll 9
    for (int k = 0; k < SC; ++k) v = v && finitef(scores[r * SC + k]);
    float cx1 = fminf(fmaxf(x1, 0.f), w);
    float cy1 = fminf(fmaxf(y1, 0.f), h);
    float cx2 = fminf(fmaxf(x2, 0.f), w);
    float cy2 = fminf(fmaxf(y2, 0.f), h);
    boxes_c[r] = make_float4(cx1, cy1, cx2, cy2);
    area[r] = fmaxf(cx2 - cx1, 0.f) * fmaxf(cy2 - cy1, 0.f);
    valid[r] = v ? 1 : 0;
}

// ---------------- kernel B: per-class NMS (one block per class) ----------------
#define NMS_THREADS 256
#define KMAX 192   // kept-list capacity: stop checked per chunk, <=99+64 entries live

__device__ __forceinline__ float iou_f(float4 a, float aa, float4 b, float ab) {
    float ltx = fmaxf(a.x, b.x), lty = fmaxf(a.y, b.y);
    float rbx = fminf(a.z, b.z), rby = fminf(a.w, b.w);
    float iw = fmaxf(rbx - ltx, 0.f), ih = fmaxf(rby - lty, 0.f);
    float inter = iw * ih;
    float uni = aa + ab - inter + 1e-9f;
    return inter / uni;
}

__global__ __launch_bounds__(NMS_THREADS) void nms_kernel(
    const float* __restrict__ scores,
    const float4* __restrict__ boxes_c,
    const float* __restrict__ area,
    const int* __restrict__ valid,
    unsigned long long* __restrict__ entries,
    unsigned int* __restrict__ counter) {
    __shared__ float s_sc[R];                 // 32 KB
    __shared__ unsigned short s_id[R];        // 16 KB
    __shared__ float4 kb[KMAX];               // 3 KB kept boxes
    __shared__ float  ka[KMAX];               // kept areas
    __shared__ unsigned int s_suppw[4][64];   // per-slice suppression flags
    __shared__ int s_cnt;
    __shared__ int s_kept;

    const int tid = threadIdx.x;
    const int k = blockIdx.x;

    if (tid == 0) { s_cnt = 0; s_kept = 0; }
    __syncthreads();

    // compact candidates: score > thresh && valid
    for (int r = tid; r < R; r += NMS_THREADS) {
        float sc = scores[r * SC + k];
        if (sc > SCORE_THRESH && valid[r]) {
            int p = atomicAdd(&s_cnt, 1);
            s_sc[p] = sc;
            s_id[p] = (unsigned short)r;
        }
    }
    __syncthreads();
    const int cnt = s_cnt;
    if (cnt == 0) return;

    int npad = 64;
    while (npad < cnt) npad <<= 1;
    for (int i = cnt + tid; i < npad; i += NMS_THREADS) {
        s_sc[i] = -INFINITY;
        s_id[i] = 0xFFFFu;
    }
    __syncthreads();

    // bitonic sort: descending score, ties -> ascending index (stable argsort(-s))
    for (int kk = 2; kk <= npad; kk <<= 1) {
        for (int j = kk >> 1; j > 0; j >>= 1) {
            for (int i = tid; i < npad; i += NMS_THREADS) {
                int ixj = i ^ j;
                if (ixj > i) {
                    float a = s_sc[i], b = s_sc[ixj];
                    unsigned short ia = s_id[i], ib = s_id[ixj];
                    bool b_before_a = (b > a) || (b == a && ib < ia);
                    bool ascending = ((i & kk) == 0);
                    if (b_before_a == ascending) {
                        s_sc[i] = b; s_sc[ixj] = a;
                        s_id[i] = ib; s_id[ixj] = ia;
                    }
                }
            }
            __syncthreads();
        }
    }

    // greedy NMS, chunks of 64 sorted candidates; early exit at 100 keeps
    const int lane = tid & 63;
    const int slice = tid >> 6;
    const int nchunks = (cnt + 63) >> 6;
    for (int c = 0; c < nchunks; ++c) {
        const int kept0 = s_kept;          // stable: last write precedes a barrier
        if (kept0 >= TOPK_N) break;        // uniform
        const int j = (c << 6) + lane;
        const bool incand = (j < cnt);
        const int bidx = incand ? (int)s_id[j] : 0;
        const float4 cb = boxes_c[bidx];
        const float car = area[bidx];

        // phase 1: test chunk candidates against kept list (4 slices in parallel)
        unsigned int sup = 0u;
        for (int t = slice; t < kept0; t += 4) {
            if (iou_f(cb, car, kb[t], ka[t]) > NMS_THRESH) sup = 1u;
        }
        s_suppw[slice][lane] = sup;
        __syncthreads();

        // phase 2: wave 0 resolves intra-chunk suppression serially in-register
        if (tid < 64) {
            bool alive = incand &&
                !(s_suppw[0][lane] | s_suppw[1][lane] | s_suppw[2][lane] | s_suppw[3][lane]);
            for (int l = 0; l < 64; ++l) {
                int al = __shfl((int)alive, l);
                if (al) {
                    float bx = __shfl(cb.x, l), by = __shfl(cb.y, l);
                    float bz = __shfl(cb.z, l), bw = __shfl(cb.w, l);
                    float ba = __shfl(car, l);
                    if (lane > l && alive) {
                        float ltx = fmaxf(cb.x, bx), lty = fmaxf(cb.y, by);
                        float rbx = fminf(cb.z, bz), rby = fminf(cb.w, bw);
                        float iw = fmaxf(rbx - ltx, 0.f), ih = fmaxf(rby - lty, 0.f);
                        float inter = iw * ih;
                        float uni = car + ba - inter + 1e-9f;
                        if (inter / uni > NMS_THRESH) alive = false;
                    }
                }
            }
            unsigned long long bal = __ballot(alive);
            int pos = kept0 + __popcll(bal & ((1ull << lane) - 1ull));
            if (alive) {
                kb[pos] = cb;
                ka[pos] = car;
                if (pos < TOPK_N) {
                    unsigned long long e =
                        ((unsigned long long)(unsigned int)(k * R + bidx) << 32) |
                        (unsigned long long)__float_as_uint(s_sc[j]);
                    entries[k * TOPK_N + pos] = e;
                }
            }
            if (lane == 0) s_kept = kept0 + (int)__popcll(bal);
        }
        __syncthreads();
    }

    if (tid == 0) {
        int addv = s_kept < TOPK_N ? s_kept : TOPK_N;
        atomicAdd(counter, (unsigned int)addv);
    }
}

// ---------------- kernel C: single-wave 80-way tournament merge ----------------
#define TK_THREADS 256

__global__ __launch_bounds__(TK_THREADS) void topk_kernel(
    const unsigned long long* __restrict__ entries,
    const unsigned int* __restrict__ counter,
    const float4* __restrict__ boxes_c,
    float* __restrict__ out) {
    __shared__ unsigned int s_key[NENT];   // 32 KB, score bits (0 for empty slots)
    __shared__ int s_sel[TOPK_N];

    const int tid = threadIdx.x;
    for (int i = tid; i < NENT; i += TK_THREADS) {
        s_key[i] = (unsigned int)entries[i];
    }
    __syncthreads();

    // wave 0: 100 selection steps over 80 sorted lists (lane -> class lane, 64+lane)
    if (tid < 64) {
        const int lane = tid;
        int p0 = 0;                 // pointer into class `lane`
        int p1 = 0;                 // pointer into class `64+lane` (lane < 16)
        for (int s = 0; s < TOPK_N; ++s) {
            unsigned int k0 = 0u; int q0 = 0x7FFFFFFF;
            if (p0 < TOPK_N) { q0 = lane * TOPK_N + p0; k0 = s_key[q0]; }
            unsigned int k1 = 0u; int q1 = 0x7FFFFFFF;
            if (lane < 16 && p1 < TOPK_N) { q1 = (64 + lane) * TOPK_N + p1; k1 = s_key[q1]; }
            unsigned int bk = k0; int bp = q0;
            if (k1 > bk || (k1 == bk && q1 < bp)) { bk = k1; bp = q1; }
            // butterfly argmax: (key desc, pos asc)
            for (int off = 32; off > 0; off >>= 1) {
                unsigned int ok = __shfl_xor(bk, off);
                int op = __shfl_xor(bp, off);
                if (ok > bk || (ok == bk && op < bp)) { bk = ok; bp = op; }
            }
            if (lane == 0) s_sel[s] = bp;
            if (p0 < TOPK_N && bp == lane * TOPK_N + p0) p0++;
            else if (lane < 16 && p1 < TOPK_N && bp == (64 + lane) * TOPK_N + p1) p1++;
        }
    }
    __syncthreads();

    if (tid < TOPK_N) {
        const int M = (int)*counter;
        const int pos = s_sel[tid];
        const bool dv = (tid < M);
        float s = __uint_as_float(s_key[pos]);
        int flat = dv ? (int)(entries[pos] >> 32) : 0;
        int r = flat & (R - 1);
        int kc = flat >> 13;
        float4 bb = dv ? boxes_c[r] : make_float4(0.f, 0.f, 0.f, 0.f);
        out[tid * 4 + 0] = bb.x;
        out[tid * 4 + 1] = bb.y;
        out[tid * 4 + 2] = bb.z;
        out[tid * 4 + 3] = bb.w;
        out[400 + tid] = dv ? s : 0.f;
        out[500 + tid] = dv ? (float)kc : -1.f;
        out[600 + tid] = dv ? (float)r : -1.f;
    }
}

extern "C" void kernel_launch(void* const* d_in, const int* in_sizes, int n_in,
                              void* d_out, int out_size, void* d_ws, size_t ws_size,
                              hipStream_t stream) {
    const float* boxes  = (const float*)d_in[0];
    const float* scores = (const float*)d_in[1];
    const int*   imh    = (const int*)d_in[2];
    const int*   imw    = (const int*)d_in[3];

    char* ws = (char*)d_ws;
    float4*             boxes_c = (float4*)(ws + BOXC_OFF);
    float*              area    = (float*)(ws + AREA_OFF);
    int*                valid   = (int*)(ws + VALID_OFF);
    unsigned int*       counter = (unsigned int*)(ws + CNT_OFF);
    unsigned long long* entries = (unsigned long long*)(ws + ENT_OFF);

    prep_kernel<<<R / 256, 256, 0, stream>>>(boxes, scores, imh, imw,
                                             boxes_c, area, valid, counter, entries);
    nms_kernel<<<NCLS, NMS_THREADS, 0, stream>>>(scores, boxes_c, area, valid,
                                                 entries, counter);
    topk_kernel<<<1, TK_THREADS, 0, stream>>>(entries, counter, boxes_c,
                                              (float*)d_out);
}

// Round 4
// 93.324 us; speedup vs baseline: 12.0093x; 1.6089x over previous
//
#include <hip/hip_runtime.h>
#include <float.h>
#include <math.h>

#pragma clang fp contract(off)

#define R 8192
#define NCLS 80
#define SC 81          // scores row width (K+1)
#define TOPK_N 100
#define SCORE_THRESH 0.05f
#define NMS_THRESH 0.5f
#define NEGV -1000000000.0f

// workspace layout (bytes)
#define BOXC_OFF   0            // float4[R]        131072
#define AREA_OFF   131072       // float[R]          32768
#define VALID_OFF  163840       // int[R]            32768
#define CNT_OFF    196608       // uint (padded)        16
#define ENT_OFF    196624       // u64 entries[NCLS*100] = 64000 bytes
#define NENT       (NCLS * TOPK_N)   // 8000

__device__ __forceinline__ bool finitef(float x) {
    return fabsf(x) <= FLT_MAX;   // false for NaN and +-inf
}

// ---------------- kernel A: clip boxes, validity, areas, zero counter+entries ------
__global__ void prep_kernel(const float* __restrict__ boxes,
                            const float* __restrict__ scores,
                            const int* __restrict__ imh,
                            const int* __restrict__ imw,
                            float4* __restrict__ boxes_c,
                            float* __restrict__ area,
                            int* __restrict__ valid,
                            unsigned int* __restrict__ counter,
                            unsigned long long* __restrict__ entries) {
    int r = blockIdx.x * blockDim.x + threadIdx.x;
    if (r == 0) *counter = 0u;
    if (r < NENT) entries[r] = 0ull;
    if (r >= R) return;
    float w = (float)(*imw), h = (float)(*imh);
    float x1 = boxes[r * 4 + 0];
    float y1 = boxes[r * 4 + 1];
    float x2 = boxes[r * 4 + 2];
    float y2 = boxes[r * 4 + 3];
    bool v = finitef(x1) && finitef(y1) && finitef(x2) && finitef(y2);
#pragma unroll 9
    for (int k = 0; k < SC; ++k) v = v && finitef(scores[r * SC + k]);
    float cx1 = fminf(fmaxf(x1, 0.f), w);
    float cy1 = fminf(fmaxf(y1, 0.f), h);
    float cx2 = fminf(fmaxf(x2, 0.f), w);
    float cy2 = fminf(fmaxf(y2, 0.f), h);
    boxes_c[r] = make_float4(cx1, cy1, cx2, cy2);
    area[r] = fmaxf(cx2 - cx1, 0.f) * fmaxf(cy2 - cy1, 0.f);
    valid[r] = v ? 1 : 0;
}

// ---------------- kernel B: per-class NMS (one block per class) ----------------
#define NMS_THREADS 256
#define KMAX 192   // kept-list capacity: stop checked per chunk, <=99+64 entries live

__device__ __forceinline__ float iou_f(float4 a, float aa, float4 b, float ab) {
    float ltx = fmaxf(a.x, b.x), lty = fmaxf(a.y, b.y);
    float rbx = fminf(a.z, b.z), rby = fminf(a.w, b.w);
    float iw = fmaxf(rbx - ltx, 0.f), ih = fmaxf(rby - lty, 0.f);
    float inter = iw * ih;
    float uni = aa + ab - inter + 1e-9f;
    return inter / uni;
}

__global__ __launch_bounds__(NMS_THREADS) void nms_kernel(
    const float* __restrict__ scores,
    const float4* __restrict__ boxes_c,
    const float* __restrict__ area,
    const int* __restrict__ valid,
    unsigned long long* __restrict__ entries,
    unsigned int* __restrict__ counter) {
    __shared__ float s_sc[R];                 // 32 KB
    __shared__ unsigned short s_id[R];        // 16 KB
    __shared__ float4 kb[KMAX];               // 3 KB kept boxes
    __shared__ float  ka[KMAX];               // kept areas
    __shared__ unsigned int s_suppw[4][64];   // per-slice suppression flags
    __shared__ int s_cnt;
    __shared__ int s_kept;

    const int tid = threadIdx.x;
    const int k = blockIdx.x;

    if (tid == 0) { s_cnt = 0; s_kept = 0; }
    __syncthreads();

    // compact candidates: score > thresh && valid
    for (int r = tid; r < R; r += NMS_THREADS) {
        float sc = scores[r * SC + k];
        if (sc > SCORE_THRESH && valid[r]) {
            int p = atomicAdd(&s_cnt, 1);
            s_sc[p] = sc;
            s_id[p] = (unsigned short)r;
        }
    }
    __syncthreads();
    const int cnt = s_cnt;
    if (cnt == 0) return;

    int npad = 64;
    while (npad < cnt) npad <<= 1;
    for (int i = cnt + tid; i < npad; i += NMS_THREADS) {
        s_sc[i] = -INFINITY;
        s_id[i] = 0xFFFFu;
    }
    __syncthreads();

    // bitonic sort: descending score, ties -> ascending index (stable argsort(-s))
    for (int kk = 2; kk <= npad; kk <<= 1) {
        for (int j = kk >> 1; j > 0; j >>= 1) {
            for (int i = tid; i < npad; i += NMS_THREADS) {
                int ixj = i ^ j;
                if (ixj > i) {
                    float a = s_sc[i], b = s_sc[ixj];
                    unsigned short ia = s_id[i], ib = s_id[ixj];
                    bool b_before_a = (b > a) || (b == a && ib < ia);
                    bool ascending = ((i & kk) == 0);
                    if (b_before_a == ascending) {
                        s_sc[i] = b; s_sc[ixj] = a;
                        s_id[i] = ib; s_id[ixj] = ia;
                    }
                }
            }
            __syncthreads();
        }
    }

    // greedy NMS, chunks of 64 sorted candidates; early exit at 100 keeps
    const int lane = tid & 63;
    const int slice = tid >> 6;
    const int nchunks = (cnt + 63) >> 6;
    for (int c = 0; c < nchunks; ++c) {
        const int kept0 = s_kept;          // stable: last write precedes a barrier
        if (kept0 >= TOPK_N) break;        // uniform
        const int j = (c << 6) + lane;
        const bool incand = (j < cnt);
        const int bidx = incand ? (int)s_id[j] : 0;
        const float4 cb = boxes_c[bidx];
        const float car = area[bidx];

        // phase 1: test chunk candidates against kept list (4 slices in parallel)
        unsigned int sup = 0u;
        for (int t = slice; t < kept0; t += 4) {
            if (iou_f(cb, car, kb[t], ka[t]) > NMS_THRESH) sup = 1u;
        }
        s_suppw[slice][lane] = sup;
        __syncthreads();

        // phase 2: wave 0 resolves intra-chunk suppression serially in-register
        if (tid < 64) {
            bool alive = incand &&
                !(s_suppw[0][lane] | s_suppw[1][lane] | s_suppw[2][lane] | s_suppw[3][lane]);
            for (int l = 0; l < 64; ++l) {
                int al = __shfl((int)alive, l);
                if (al) {
                    float bx = __shfl(cb.x, l), by = __shfl(cb.y, l);
                    float bz = __shfl(cb.z, l), bw = __shfl(cb.w, l);
                    float ba = __shfl(car, l);
                    if (lane > l && alive) {
                        float ltx = fmaxf(cb.x, bx), lty = fmaxf(cb.y, by);
                        float rbx = fminf(cb.z, bz), rby = fminf(cb.w, bw);
                        float iw = fmaxf(rbx - ltx, 0.f), ih = fmaxf(rby - lty, 0.f);
                        float inter = iw * ih;
                        float uni = car + ba - inter + 1e-9f;
                        if (inter / uni > NMS_THRESH) alive = false;
                    }
                }
            }
            unsigned long long bal = __ballot(alive);
            int pos = kept0 + __popcll(bal & ((1ull << lane) - 1ull));
            if (alive) {
                kb[pos] = cb;
                ka[pos] = car;
                if (pos < TOPK_N) {
                    unsigned long long e =
                        ((unsigned long long)(unsigned int)(k * R + bidx) << 32) |
                        (unsigned long long)__float_as_uint(s_sc[j]);
                    entries[k * TOPK_N + pos] = e;
                }
            }
            if (lane == 0) s_kept = kept0 + (int)__popcll(bal);
        }
        __syncthreads();
    }

    if (tid == 0) {
        int addv = s_kept < TOPK_N ? s_kept : TOPK_N;
        atomicAdd(counter, (unsigned int)addv);
    }
}

// ---------------- kernel C: radix-select top-100 of 8000 + output ----------------
// Real keys are float bits of scores in (0.05, 1] -> bits 31..26 == 0x0F, 26 bits
// of entropy. Empty slots are key 0. 3 histogram levels: bits 25..18, 17..10, 9..0.
#define TK_THREADS 256
#define TIECAP 512

__global__ __launch_bounds__(TK_THREADS) void topk_kernel(
    const unsigned long long* __restrict__ entries,
    const unsigned int* __restrict__ counter,
    const float4* __restrict__ boxes_c,
    float* __restrict__ out) {
    __shared__ unsigned int hist[4 * 1024];   // wave-private, 16 KB
    __shared__ unsigned int wt[4];
    __shared__ unsigned int s_binr[2];        // {bin, remaining rank}
    __shared__ unsigned int selk[TOPK_N];
    __shared__ int          selp[TOPK_N];
    __shared__ unsigned int fkey[TOPK_N];
    __shared__ int          fpos[TOPK_N];
    __shared__ int          tiepos[TIECAP];
    __shared__ unsigned int a_gt, a_tie;

    const int tid = threadIdx.x;
    const int wave = tid >> 6, lane = tid & 63;
    const unsigned int* e32 = (const unsigned int*)entries;

    // 8000 keys into registers (static-indexed array)
    unsigned int key[32];
#pragma unroll
    for (int i = 0; i < 32; ++i) {
        int idx = i * TK_THREADS + tid;
        key[i] = (idx < NENT) ? e32[2 * idx] : 0u;
    }
    const int M = (int)*counter;
    if (tid == 0) { a_gt = 0u; a_tie = 0u; }
    if (tid < TOPK_N) { fkey[tid] = 0u; fpos[tid] = 0; }

    unsigned int T = 0u;
    unsigned int needed_ties = 0u;
    if (M >= TOPK_N) {
        unsigned int r = TOPK_N;      // rank sought among participants, 1-based
        unsigned int P = 0x0Fu;       // required value of key >> hi
        int hi = 26;
        const int nbits_arr[3] = {8, 8, 10};
        for (int lvl = 0; lvl < 3; ++lvl) {
            const int nbits = nbits_arr[lvl];
            const int nb = 1 << nbits;
            const int sh = hi - nbits;
            for (int j = tid; j < 4 * 1024; j += TK_THREADS) hist[j] = 0u;
            __syncthreads();
            unsigned int* hw = &hist[wave * 1024];
#pragma unroll
            for (int i = 0; i < 32; ++i) {
                unsigned int kv = key[i];
                if ((kv >> hi) == P) atomicAdd(&hw[(kv >> sh) & (nb - 1)], 1u);
            }
            __syncthreads();
            // per-thread group of G bins; suffix scan to locate target bin
            const int G = nb >> 8;
            unsigned int g = 0u;
            for (int b = 0; b < G; ++b) {
                int bin = tid * G + b;
                g += hist[bin] + hist[1024 + bin] + hist[2048 + bin] + hist[3072 + bin];
            }
            unsigned int S = g;  // wave-level inclusive suffix sum
            for (int off = 1; off < 64; off <<= 1) {
                unsigned int v = __shfl_down(S, off);
                if (lane + off < 64) S += v;
            }
            if (lane == 0) wt[wave] = S;
            __syncthreads();
            unsigned int above_w = 0u;
            for (int w2 = wave + 1; w2 < 4; ++w2) above_w += wt[w2];
            unsigned int Sown = S + above_w;     // suffix incl. my group
            unsigned int above = Sown - g;       // suffix excl. my group
            if (above < r && r <= Sown) {        // exactly one thread matches
                unsigned int cum = above;
                for (int b = G - 1; b >= 0; --b) {
                    int bin = tid * G + b;
                    unsigned int tb = hist[bin] + hist[1024 + bin] +
                                      hist[2048 + bin] + hist[3072 + bin];
                    cum += tb;
                    if (cum >= r) {
                        s_binr[0] = (unsigned int)bin;
                        s_binr[1] = r - (cum - tb);
                        break;
                    }
                }
            }
            __syncthreads();
            P = (P << nbits) | s_binr[0];
            r = s_binr[1];
            hi = sh;
            __syncthreads();
        }
        T = P;                 // exact 100th-largest key
        needed_ties = r;       // how many ties at T to take (pos-ascending)
    }
    __syncthreads();

    // collect entries > T (unordered) and ties at T
    const unsigned int Teff = (M >= TOPK_N) ? T : 0u;
    if (M > 0) {
#pragma unroll
        for (int i = 0; i < 32; ++i) {
            unsigned int kv = key[i];
            int pos = i * TK_THREADS + tid;
            if (kv > Teff) {
                unsigned int p = atomicAdd(&a_gt, 1u);
                selk[p] = kv; selp[p] = pos;
            } else if (M >= TOPK_N && kv == Teff) {
                unsigned int q = atomicAdd(&a_tie, 1u);
                if (q < TIECAP) tiepos[q] = pos;
            }
        }
    }
    __syncthreads();
    const unsigned int ngt = a_gt;
    if (M >= TOPK_N && needed_ties > 0u) {
        unsigned int ntie = a_tie < TIECAP ? a_tie : TIECAP;
        for (unsigned int j = tid; j < ntie; j += TK_THREADS) {
            int pj = tiepos[j];
            unsigned int rnk = 0u;
            for (unsigned int j2 = 0; j2 < ntie; ++j2) rnk += (tiepos[j2] < pj);
            if (rnk < needed_ties) { selk[ngt + rnk] = T; selp[ngt + rnk] = pj; }
        }
    }
    __syncthreads();

    const int SELN = (M >= TOPK_N) ? TOPK_N : M;
    // rank the exactly-SELN selected entries: (key desc, pos asc)
    if (tid < SELN) {
        unsigned int kk = selk[tid];
        int pp = selp[tid];
        unsigned int rnk = 0u;
        for (int j = 0; j < SELN; ++j) {
            unsigned int kj = selk[j];
            int pj = selp[j];
            rnk += (kj > kk) || (kj == kk && pj < pp);
        }
        fkey[rnk] = kk;
        fpos[rnk] = pp;
    }
    __syncthreads();

    if (tid < TOPK_N) {
        bool dv = (tid < SELN);
        int pos = fpos[tid];
        float s = __uint_as_float(fkey[tid]);
        int flat = dv ? (int)e32[2 * pos + 1] : 0;
        int r = flat & (R - 1);
        int kc = flat >> 13;
        float4 bb = dv ? boxes_c[r] : make_float4(0.f, 0.f, 0.f, 0.f);
        out[tid * 4 + 0] = bb.x;
        out[tid * 4 + 1] = bb.y;
        out[tid * 4 + 2] = bb.z;
        out[tid * 4 + 3] = bb.w;
        out[400 + tid] = dv ? s : 0.f;
        out[500 + tid] = dv ? (float)kc : -1.f;
        out[600 + tid] = dv ? (float)r : -1.f;
    }
}

extern "C" void kernel_launch(void* const* d_in, const int* in_sizes, int n_in,
                              void* d_out, int out_size, void* d_ws, size_t ws_size,
                              hipStream_t stream) {
    const float* boxes  = (const float*)d_in[0];
    const float* scores = (const float*)d_in[1];
    const int*   imh    = (const int*)d_in[2];
    const int*   imw    = (const int*)d_in[3];

    char* ws = (char*)d_ws;
    float4*             boxes_c = (float4*)(ws + BOXC_OFF);
    float*              area    = (float*)(ws + AREA_OFF);
    int*                valid   = (int*)(ws + VALID_OFF);
    unsigned int*       counter = (unsigned int*)(ws + CNT_OFF);
    unsigned long long* entries = (unsigned long long*)(ws + ENT_OFF);

    prep_kernel<<<R / 256, 256, 0, stream>>>(boxes, scores, imh, imw,
                                             boxes_c, area, valid, counter, entries);
    nms_kernel<<<NCLS, NMS_THREADS, 0, stream>>>(scores, boxes_c, area, valid,
                                                 entries, counter);
    topk_kernel<<<1, TK_THREADS, 0, stream>>>(entries, counter, boxes_c,
                                              (float*)d_out);
}

// Round 5
// 59.900 us; speedup vs baseline: 18.7105x; 1.5580x over previous
//
#include <hip/hip_runtime.h>
#include <float.h>
#include <math.h>

#pragma clang fp contract(off)

#define R 8192
#define NCLS 80
#define SC 81          // scores row width (K+1)
#define TOPK_N 100
#define SCORE_THRESH 0.05f
#define NMS_THRESH 0.5f

// workspace layout (bytes)
#define BOXC_OFF   0            // float4[R]              131072
#define AREA_OFF   131072       // float[R] (<0 ⇒ row invalid)
#define CNT_OFF    163840       // uint (padded to 256)
#define ENT_OFF    164096       // u64 entries[NCLS*100] = 64000
#define ST_OFF     228352       // float scores_T[NCLS][R] = 2621440
#define NENT       (NCLS * TOPK_N)   // 8000

__device__ __forceinline__ bool finitef(float x) {
    return fabsf(x) <= FLT_MAX;   // false for NaN and +-inf
}

__device__ __forceinline__ float iou_f(float4 a, float aa, float4 b, float ab) {
    float ltx = fmaxf(a.x, b.x), lty = fmaxf(a.y, b.y);
    float rbx = fminf(a.z, b.z), rby = fminf(a.w, b.w);
    float iw = fmaxf(rbx - ltx, 0.f), ih = fmaxf(rby - lty, 0.f);
    float inter = iw * ih;
    float uni = aa + ab - inter + 1e-9f;
    return inter / uni;
}

// key packing: (score_bits << 13) | (8191 - r)  -> u64 desc == (score desc, r asc)
__device__ __forceinline__ unsigned long long pack_key(float sc, int r) {
    return ((unsigned long long)__float_as_uint(sc) << 13) |
           (unsigned long long)(8191 - r);
}

// ---------------- kernel A: coalesced prep (clip, validity, transpose) -------------
#define PREP_ROWS 32
#define PREP_THREADS 256

__global__ __launch_bounds__(PREP_THREADS) void prep_kernel(
    const float* __restrict__ boxes,
    const float* __restrict__ scores,
    const int* __restrict__ imh,
    const int* __restrict__ imw,
    float4* __restrict__ boxes_c,
    float* __restrict__ area,
    unsigned int* __restrict__ counter,
    unsigned long long* __restrict__ entries,
    float* __restrict__ scores_t,
    int do_t) {
    __shared__ float s_sc[PREP_ROWS * SC];   // 10368 B
    __shared__ int s_vld[PREP_ROWS];

    const int tid = threadIdx.x;
    const int blk = blockIdx.x;
    const int r0 = blk * PREP_ROWS;

    if (blk == 0 && tid == 0) *counter = 0u;
    {   // zero the 8000 entry slots across the first 32 blocks
        int i = blk * PREP_THREADS + tid;
        if (i < NENT) entries[i] = 0ull;
    }
    if (tid < PREP_ROWS) s_vld[tid] = 1;
    __syncthreads();

    // coalesced load of 32 rows x 81 scores; finiteness folded via LDS atomics
    const float* src = scores + (size_t)r0 * SC;
    for (int idx = tid; idx < PREP_ROWS * SC; idx += PREP_THREADS) {
        float v = src[idx];
        s_sc[idx] = v;
        if (!finitef(v)) atomicAnd(&s_vld[idx / SC], 0);
    }

    // boxes: 32 coalesced float4 loads
    float4 bc = make_float4(0.f, 0.f, 0.f, 0.f);
    float ar = 0.f;
    int bok = 1;
    if (tid < PREP_ROWS) {
        float4 b = ((const float4*)boxes)[r0 + tid];
        bok = finitef(b.x) && finitef(b.y) && finitef(b.z) && finitef(b.w);
        float w = (float)(*imw), h = (float)(*imh);
        bc.x = fminf(fmaxf(b.x, 0.f), w);
        bc.y = fminf(fmaxf(b.y, 0.f), h);
        bc.z = fminf(fmaxf(b.z, 0.f), w);
        bc.w = fminf(fmaxf(b.w, 0.f), h);
        ar = fmaxf(bc.z - bc.x, 0.f) * fmaxf(bc.w - bc.y, 0.f);
    }
    __syncthreads();
    if (tid < PREP_ROWS) {
        int v = s_vld[tid] && bok;
        s_vld[tid] = v;
        boxes_c[r0 + tid] = bc;
        area[r0 + tid] = v ? ar : -1.0f;   // sign marks invalid rows
    }
    __syncthreads();

    if (do_t) {
        // transposed store: scores_t[k][r0+rr], validity folded as -1
        for (int idx = tid; idx < NCLS * PREP_ROWS; idx += PREP_THREADS) {
            int k = idx >> 5;
            int rr = idx & 31;
            float v = s_sc[rr * SC + k];
            if (!s_vld[rr]) v = -1.0f;
            scores_t[(size_t)k * R + r0 + rr] = v;
        }
    }
}

// ---------------- kernel B: per-class NMS (one block per class) ----------------
#define NMS_THREADS 256
#define KMAX 192   // kept-list cap: kept0<100 at chunk entry, +<=64 per chunk

__global__ __launch_bounds__(NMS_THREADS) void nms_kernel(
    const float* __restrict__ scores,
    const float* __restrict__ scores_t,
    int use_t,
    const float4* __restrict__ boxes_c,
    const float* __restrict__ area,
    unsigned long long* __restrict__ entries,
    unsigned int* __restrict__ counter) {
    __shared__ unsigned long long s_key[R];   // 64 KB
    __shared__ float4 kb[KMAX];
    __shared__ float  ka[KMAX];
    __shared__ float4 s_cb[64];
    __shared__ float  s_car[64];
    __shared__ unsigned int s_part[4][64];
    __shared__ unsigned int s_sup1[4][64];
    __shared__ int s_cnt, s_kept;

    const int tid = threadIdx.x;
    const int k = blockIdx.x;

    if (tid == 0) { s_cnt = 0; s_kept = 0; }
    __syncthreads();

    // compact candidates
    if (use_t) {
        const float4* col = (const float4*)(scores_t + (size_t)k * R);
        for (int i = tid; i < R / 4; i += NMS_THREADS) {
            float4 v = col[i];
            int r = i * 4;
            if (v.x > SCORE_THRESH) { int p = atomicAdd(&s_cnt, 1); s_key[p] = pack_key(v.x, r); }
            if (v.y > SCORE_THRESH) { int p = atomicAdd(&s_cnt, 1); s_key[p] = pack_key(v.y, r + 1); }
            if (v.z > SCORE_THRESH) { int p = atomicAdd(&s_cnt, 1); s_key[p] = pack_key(v.z, r + 2); }
            if (v.w > SCORE_THRESH) { int p = atomicAdd(&s_cnt, 1); s_key[p] = pack_key(v.w, r + 3); }
        }
    } else {
        for (int r = tid; r < R; r += NMS_THREADS) {
            float sc = scores[(size_t)r * SC + k];
            if (sc > SCORE_THRESH && area[r] >= 0.f) {
                int p = atomicAdd(&s_cnt, 1);
                s_key[p] = pack_key(sc, r);
            }
        }
    }
    __syncthreads();
    const int cnt = s_cnt;
    if (cnt == 0) return;

    int npad = 64;
    while (npad < cnt) npad <<= 1;
    for (int i = cnt + tid; i < npad; i += NMS_THREADS) s_key[i] = 0ull;
    __syncthreads();

    // bitonic sort, u64 keys, descending
    for (int kk = 2; kk <= npad; kk <<= 1) {
        for (int j = kk >> 1; j > 0; j >>= 1) {
            for (int i = tid; i < npad; i += NMS_THREADS) {
                int ixj = i ^ j;
                if (ixj > i) {
                    unsigned long long a = s_key[i], b = s_key[ixj];
                    bool ascending = ((i & kk) == 0);
                    if ((b > a) == ascending) { s_key[i] = b; s_key[ixj] = a; }
                }
            }
            __syncthreads();
        }
    }

    // greedy NMS, chunks of 64; early exit at 100 keeps
    const int lane = tid & 63;
    const int wv = tid >> 6;
    const int nchunks = (cnt + 63) >> 6;
    for (int c = 0; c < nchunks; ++c) {
        const int kept0 = s_kept;
        if (kept0 >= TOPK_N) break;       // uniform
        const int j = (c << 6) + lane;
        const bool incand = (j < cnt);

        if (tid < 64) {                    // stage chunk boxes into LDS
            float4 cb = make_float4(0.f, 0.f, 0.f, 0.f);
            float car = 0.f;
            if (incand) {
                int bidx = 8191 - (int)(s_key[j] & 8191ull);
                cb = boxes_c[bidx];
                car = area[bidx];
            }
            s_cb[lane] = cb;
            s_car[lane] = car;
        }
        __syncthreads();

        {   // parallel: kept-list test (slice over waves) + 64x64 adjacency partials
            float4 cb = s_cb[lane];
            float car = s_car[lane];
            unsigned int sup = 0u;
            for (int t = wv; t < kept0; t += 4)
                if (iou_f(cb, car, kb[t], ka[t]) > NMS_THRESH) sup = 1u;
            s_sup1[wv][lane] = sup;
            unsigned int pm = 0u;
            const int i0 = wv << 4;
#pragma unroll
            for (int ii = 0; ii < 16; ++ii) {
                int i = i0 + ii;
                if (i != lane && iou_f(cb, car, s_cb[i], s_car[i]) > NMS_THRESH)
                    pm |= 1u << ii;
            }
            s_part[wv][lane] = pm;
        }
        __syncthreads();

        if (tid < 64) {                    // wave 0: bitmask greedy resolve
            bool sup1 = (s_sup1[0][lane] | s_sup1[1][lane] |
                         s_sup1[2][lane] | s_sup1[3][lane]) != 0u;
            unsigned long long supmask =
                 (unsigned long long)s_part[0][lane]
               | ((unsigned long long)s_part[1][lane] << 16)
               | ((unsigned long long)s_part[2][lane] << 32)
               | ((unsigned long long)s_part[3][lane] << 48);
            bool alive0 = incand && !sup1;
            unsigned long long av = __ballot(alive0);
            unsigned long long kept = 0ull;
#pragma unroll
            for (int l = 0; l < 64; ++l) {
                unsigned long long m = __shfl(supmask, l);  // indep of `kept`
                if (((av >> l) & 1ull) && !(m & kept)) kept |= 1ull << l;
            }
            if ((kept >> lane) & 1ull) {
                int pos = kept0 + (int)__popcll(kept & ((1ull << lane) - 1ull));
                kb[pos] = s_cb[lane];
                ka[pos] = s_car[lane];
                if (pos < TOPK_N) {
                    unsigned long long kv = s_key[j];
                    int bidx = 8191 - (int)(kv & 8191ull);
                    unsigned int sb = (unsigned int)(kv >> 13);
                    entries[k * TOPK_N + pos] =
                        ((unsigned long long)(unsigned int)(k * R + bidx) << 32) |
                        (unsigned long long)sb;
                }
            }
            if (lane == 0) s_kept = kept0 + (int)__popcll(kept);
        }
        __syncthreads();
    }

    if (tid == 0) {
        int addv = s_kept < TOPK_N ? s_kept : TOPK_N;
        atomicAdd(counter, (unsigned int)addv);
    }
}

// ---------------- kernel C: radix-select top-100 of 8000 + output ----------------
#define TK_THREADS 256
#define TIECAP 512

__global__ __launch_bounds__(TK_THREADS) void topk_kernel(
    const unsigned long long* __restrict__ entries,
    const unsigned int* __restrict__ counter,
    const float4* __restrict__ boxes_c,
    float* __restrict__ out) {
    __shared__ unsigned int hist[4 * 1024];   // wave-private, 16 KB
    __shared__ unsigned int wt[4];
    __shared__ unsigned int s_binr[2];        // {bin, remaining rank}
    __shared__ unsigned int selk[TOPK_N];
    __shared__ int          selp[TOPK_N];
    __shared__ unsigned int fkey[TOPK_N];
    __shared__ int          fpos[TOPK_N];
    __shared__ int          tiepos[TIECAP];
    __shared__ unsigned int a_gt, a_tie;

    const int tid = threadIdx.x;
    const int wave = tid >> 6, lane = tid & 63;
    const unsigned int* e32 = (const unsigned int*)entries;

    unsigned int key[32];
#pragma unroll
    for (int i = 0; i < 32; ++i) {
        int idx = i * TK_THREADS + tid;
        key[i] = (idx < NENT) ? e32[2 * idx] : 0u;
    }
    const int M = (int)*counter;
    if (tid == 0) { a_gt = 0u; a_tie = 0u; }
    if (tid < TOPK_N) { fkey[tid] = 0u; fpos[tid] = 0; }

    unsigned int T = 0u;
    unsigned int needed_ties = 0u;
    if (M >= TOPK_N) {
        unsigned int r = TOPK_N;
        unsigned int P = 0x0Fu;       // keys are floats in (0.05,1]: bits 31..26
        int hi = 26;
        const int nbits_arr[3] = {8, 8, 10};
        for (int lvl = 0; lvl < 3; ++lvl) {
            const int nbits = nbits_arr[lvl];
            const int nb = 1 << nbits;
            const int sh = hi - nbits;
            for (int j = tid; j < 4 * 1024; j += TK_THREADS) hist[j] = 0u;
            __syncthreads();
            unsigned int* hw = &hist[wave * 1024];
#pragma unroll
            for (int i = 0; i < 32; ++i) {
                unsigned int kv = key[i];
                if ((kv >> hi) == P) atomicAdd(&hw[(kv >> sh) & (nb - 1)], 1u);
            }
            __syncthreads();
            const int G = nb >> 8;
            unsigned int g = 0u;
            for (int b = 0; b < G; ++b) {
                int bin = tid * G + b;
                g += hist[bin] + hist[1024 + bin] + hist[2048 + bin] + hist[3072 + bin];
            }
            unsigned int S = g;
            for (int off = 1; off < 64; off <<= 1) {
                unsigned int v = __shfl_down(S, off);
                if (lane + off < 64) S += v;
            }
            if (lane == 0) wt[wave] = S;
            __syncthreads();
            unsigned int above_w = 0u;
            for (int w2 = wave + 1; w2 < 4; ++w2) above_w += wt[w2];
            unsigned int Sown = S + above_w;
            unsigned int above = Sown - g;
            if (above < r && r <= Sown) {
                unsigned int cum = above;
                for (int b = G - 1; b >= 0; --b) {
                    int bin = tid * G + b;
                    unsigned int tb = hist[bin] + hist[1024 + bin] +
                                      hist[2048 + bin] + hist[3072 + bin];
                    cum += tb;
                    if (cum >= r) {
                        s_binr[0] = (unsigned int)bin;
                        s_binr[1] = r - (cum - tb);
                        break;
                    }
                }
            }
            __syncthreads();
            P = (P << nbits) | s_binr[0];
            r = s_binr[1];
            hi = sh;
            __syncthreads();
        }
        T = P;
        needed_ties = r;
    }
    __syncthreads();

    const unsigned int Teff = (M >= TOPK_N) ? T : 0u;
    if (M > 0) {
#pragma unroll
        for (int i = 0; i < 32; ++i) {
            unsigned int kv = key[i];
            int pos = i * TK_THREADS + tid;
            if (kv > Teff) {
                unsigned int p = atomicAdd(&a_gt, 1u);
                selk[p] = kv; selp[p] = pos;
            } else if (M >= TOPK_N && kv == Teff) {
                unsigned int q = atomicAdd(&a_tie, 1u);
                if (q < TIECAP) tiepos[q] = pos;
            }
        }
    }
    __syncthreads();
    const unsigned int ngt = a_gt;
    if (M >= TOPK_N && needed_ties > 0u) {
        unsigned int ntie = a_tie < TIECAP ? a_tie : TIECAP;
        for (unsigned int j = tid; j < ntie; j += TK_THREADS) {
            int pj = tiepos[j];
            unsigned int rnk = 0u;
            for (unsigned int j2 = 0; j2 < ntie; ++j2) rnk += (tiepos[j2] < pj);
            if (rnk < needed_ties) { selk[ngt + rnk] = T; selp[ngt + rnk] = pj; }
        }
    }
    __syncthreads();

    const int SELN = (M >= TOPK_N) ? TOPK_N : M;
    if (tid < SELN) {
        unsigned int kk = selk[tid];
        int pp = selp[tid];
        unsigned int rnk = 0u;
        for (int j = 0; j < SELN; ++j) {
            unsigned int kj = selk[j];
            int pj = selp[j];
            rnk += (kj > kk) || (kj == kk && pj < pp);
        }
        fkey[rnk] = kk;
        fpos[rnk] = pp;
    }
    __syncthreads();

    if (tid < TOPK_N) {
        bool dv = (tid < SELN);
        int pos = fpos[tid];
        float s = __uint_as_float(fkey[tid]);
        int flat = dv ? (int)e32[2 * pos + 1] : 0;
        int r = flat & (R - 1);
        int kc = flat >> 13;
        float4 bb = dv ? boxes_c[r] : make_float4(0.f, 0.f, 0.f, 0.f);
        out[tid * 4 + 0] = bb.x;
        out[tid * 4 + 1] = bb.y;
        out[tid * 4 + 2] = bb.z;
        out[tid * 4 + 3] = bb.w;
        out[400 + tid] = dv ? s : 0.f;
        out[500 + tid] = dv ? (float)kc : -1.f;
        out[600 + tid] = dv ? (float)r : -1.f;
    }
}

extern "C" void kernel_launch(void* const* d_in, const int* in_sizes, int n_in,
                              void* d_out, int out_size, void* d_ws, size_t ws_size,
                              hipStream_t stream) {
    const float* boxes  = (const float*)d_in[0];
    const float* scores = (const float*)d_in[1];
    const int*   imh    = (const int*)d_in[2];
    const int*   imw    = (const int*)d_in[3];

    char* ws = (char*)d_ws;
    float4*             boxes_c  = (float4*)(ws + BOXC_OFF);
    float*              area     = (float*)(ws + AREA_OFF);
    unsigned int*       counter  = (unsigned int*)(ws + CNT_OFF);
    unsigned long long* entries  = (unsigned long long*)(ws + ENT_OFF);
    float*              scores_t = (float*)(ws + ST_OFF);

    const size_t needed = (size_t)ST_OFF + (size_t)NCLS * R * sizeof(float);
    const int use_t = (ws_size >= needed) ? 1 : 0;

    prep_kernel<<<R / PREP_ROWS, PREP_THREADS, 0, stream>>>(
        boxes, scores, imh, imw, boxes_c, area, counter, entries, scores_t, use_t);
    nms_kernel<<<NCLS, NMS_THREADS, 0, stream>>>(
        scores, scores_t, use_t, boxes_c, area, entries, counter);
    topk_kernel<<<1, TK_THREADS, 0, stream>>>(entries, counter, boxes_c,
                                              (float*)d_out);
}